// Round 15
// baseline (2289.361 us; speedup 1.0000x reference)
//
#include <hip/hip_runtime.h>
#include <hip/hip_bf16.h>

#define D_DIM 3072
#define NTRAIN 16384
#define NTEST 8192

typedef __attribute__((ext_vector_type(8))) short short8;
typedef __attribute__((ext_vector_type(4))) float f32x4;
typedef __attribute__((ext_vector_type(2))) long long ll2;

__device__ __forceinline__ unsigned short f2bf(float f) {
  union { float f; unsigned u; } x; x.f = f;
  unsigned r = x.u + 0x7FFFu + ((x.u >> 16) & 1u);
  return (unsigned short)(r >> 16);
}

__device__ __forceinline__ void gload16(const void* g, void* l) {
  __builtin_amdgcn_global_load_lds(
      (const __attribute__((address_space(1))) void*)g,
      (__attribute__((address_space(3))) void*)l, 16, 0, 0);
}

// T1: bijective chunked XCD swizzle + 8x8 supertile ordering (gx%8==0, gy%8==0).
__device__ __forceinline__ void swz_tile(int& tileY, int& tileX) {
  const int gx = gridDim.x, gy = gridDim.y;
  const int L = blockIdx.y * gx + blockIdx.x;
  const int q = (gx * gy) >> 3;
  const int s = (L & 7) * q + (L >> 3);
  const int sid = s >> 6;
  const int t = s & 63;
  const int scols = gx >> 3;
  const int sy = sid / scols, sx = sid - sy * scols;
  tileY = sy * 8 + (t >> 3);
  tileX = sx * 8 + (t & 7);
}

// ---------------- pass 0 ----------------
__global__ void k_convert(const float* __restrict__ in, unsigned short* __restrict__ out, long n4) {
  long i = (long)blockIdx.x * blockDim.x + threadIdx.x;
  long stride = (long)gridDim.x * blockDim.x;
  for (; i < n4; i += stride) {
    float4 v = reinterpret_cast<const float4*>(in)[i];
    ushort4 o;
    o.x = f2bf(v.x); o.y = f2bf(v.y); o.z = f2bf(v.z); o.w = f2bf(v.w);
    reinterpret_cast<ushort4*>(out)[i] = o;
  }
}

// f32 -> fp8 e4m3 (OCP, saturating), 8 elems/thread-iter
__global__ void k_convert8(const float* __restrict__ in, unsigned char* __restrict__ out, long n8) {
  long i = (long)blockIdx.x * blockDim.x + threadIdx.x;
  long stride = (long)gridDim.x * blockDim.x;
  for (; i < n8; i += stride) {
    float4 a = reinterpret_cast<const float4*>(in)[i * 2];
    float4 b = reinterpret_cast<const float4*>(in)[i * 2 + 1];
    int w0 = __builtin_amdgcn_cvt_pk_fp8_f32(a.x, a.y, 0, false);
    w0 = __builtin_amdgcn_cvt_pk_fp8_f32(a.z, a.w, w0, true);
    int w1 = __builtin_amdgcn_cvt_pk_fp8_f32(b.x, b.y, 0, false);
    w1 = __builtin_amdgcn_cvt_pk_fp8_f32(b.z, b.w, w1, true);
    reinterpret_cast<int2*>(out)[i] = make_int2(w0, w1);
  }
}

__global__ void k_copy4(const float4* __restrict__ in, float4* __restrict__ out, long n4) {
  long i = (long)blockIdx.x * blockDim.x + threadIdx.x;
  long stride = (long)gridDim.x * blockDim.x;
  for (; i < n4; i += stride) out[i] = in[i];
}

__global__ void k_transpose_bf16(const float* __restrict__ M, unsigned short* __restrict__ Mt) {
  __shared__ float t[32][33];
  int bx = blockIdx.x * 32, by = blockIdx.y * 32;
  int tx = threadIdx.x, ty = threadIdx.y;
#pragma unroll
  for (int i = 0; i < 32; i += 8)
    t[ty + i][tx] = M[(size_t)(by + ty + i) * D_DIM + bx + tx];
  __syncthreads();
#pragma unroll
  for (int i = 0; i < 32; i += 8)
    Mt[(size_t)(bx + ty + i) * D_DIM + by + tx] = f2bf(t[tx][ty + i]);
}

// ------- R6 xm main loop: 512 threads, 32x64 wave tiles, bf16, T2 swizzle -------
__device__ __forceinline__ void mainloopXM(const unsigned short* __restrict__ A,
                                           const unsigned short* __restrict__ B,
                                           int K, int rowBase, int colBase,
                                           unsigned short* As, unsigned short* Bs,
                                           f32x4 acc[2][4]) {
  const int tid = threadIdx.x;
  const int lane = tid & 63;
  const int wave = tid >> 6;
  const int wm = wave >> 1, wn = wave & 1;
  const int sr = tid >> 3;
  const int ssl = tid & 7;
  const int scol = ((ssl ^ (sr & 7)) * 8);
  const unsigned short* ga = A + (size_t)(rowBase + sr) * K + scol;
  const unsigned short* gb = B + (size_t)(colBase + sr) * K + scol;
  const int arow = wm * 32 + (lane & 15);
  const int brow = wn * 64 + (lane & 15);
  const int lsw = lane & 7;
  const int lhi = lane >> 4;
  for (int k0 = 0; k0 < K; k0 += 64) {
#pragma unroll
    for (int c = 0; c < 2; ++c) {
      gload16(ga + (size_t)c * 64 * K + k0, As + c * 4096 + tid * 8);
      gload16(gb + (size_t)c * 64 * K + k0, Bs + c * 4096 + tid * 8);
    }
    __syncthreads();
#pragma unroll
    for (int kk = 0; kk < 2; ++kk) {
      short8 af[2], bfr[4];
      const int sl = ((lhi + kk * 4) ^ lsw) * 8;
#pragma unroll
      for (int i = 0; i < 2; ++i)
        af[i] = *reinterpret_cast<const short8*>(&As[(arow + i * 16) * 64 + sl]);
#pragma unroll
      for (int j = 0; j < 4; ++j)
        bfr[j] = *reinterpret_cast<const short8*>(&Bs[(brow + j * 16) * 64 + sl]);
#pragma unroll
      for (int i = 0; i < 2; ++i)
#pragma unroll
        for (int j = 0; j < 4; ++j)
          acc[i][j] = __builtin_amdgcn_mfma_f32_16x16x32_bf16(af[i], bfr[j], acc[i][j], 0, 0, 0);
    }
    __syncthreads();
  }
}

// ---- GEMM1: X @ M (R6-exact). Epilogue: norm2 (+ optional fp8 sM write) ----
template <bool WRITE_SM>
__global__ __launch_bounds__(512, 4) void k_gemm_xm(const unsigned short* __restrict__ A,
                                                    const unsigned short* __restrict__ Bt,
                                                    const float* __restrict__ Xf,
                                                    unsigned char* __restrict__ smOut,
                                                    float* __restrict__ norm) {
  __shared__ unsigned short As[128 * 64], Bs[128 * 64];
  int tileY, tileX;
  swz_tile(tileY, tileX);
  const int rowBase = tileY * 128, colBase = tileX * 128;
  f32x4 acc[2][4] = {};
  mainloopXM(A, Bt, D_DIM, rowBase, colBase, As, Bs, acc);
  const int tid = threadIdx.x, lane = tid & 63;
  const int wave = tid >> 6;
  const int wm = wave >> 1, wn = wave & 1;
  const int r0 = wm * 32 + (lane >> 4) * 4;
  const int c0 = colBase + wn * 64 + (lane & 15);
#pragma unroll
  for (int mi = 0; mi < 2; ++mi) {
#pragma unroll
    for (int r = 0; r < 4; ++r) {
      const size_t grow = rowBase + r0 + mi * 16 + r;
      float v = 0.f;
#pragma unroll
      for (int ni = 0; ni < 4; ++ni) {
        float a = acc[mi][ni][r];
        int gcol = c0 + ni * 16;
        v += a * Xf[grow * D_DIM + gcol];
        if (WRITE_SM) {
          int p = __builtin_amdgcn_cvt_pk_fp8_f32(a, a, 0, false);
          smOut[grow * D_DIM + gcol] = (unsigned char)(p & 0xFF);
        }
      }
      v += __shfl_xor(v, 1); v += __shfl_xor(v, 2);
      v += __shfl_xor(v, 4); v += __shfl_xor(v, 8);
      if ((lane & 15) == 0) atomicAdd(&norm[grow], v);
    }
  }
}

// ======== GEMM2: fp8 e4m3, 256x256 tile, BK=128, m201-style 8-phase schedule ========
// 8 waves (2M x 4N), wave tile 128x64, acc[8][4]=128 regs. LDS 128 KiB dbuf.
// Phase (kp,mq): reads 2 A-frags (+4 B-frags at mq==0) as b128 (ll2 = 2 MFMA ops),
// issues 2 stage gloads for tile t+1 during phases 0-3 (>=4 phases of flight),
// then barrier / setprio+16 MFMA+setprio / barrier. Tile start: vmcnt(0)+barrier.
// 128-B rows, phys slot = l ^ (row&7) (R13's measured-0-conflict layout).
__global__ __launch_bounds__(512, 2) void k_gemm_cross(const unsigned char* __restrict__ sM8,
                                                       const unsigned char* __restrict__ xte8,
                                                       const float* __restrict__ Y,
                                                       const float* __restrict__ sn2,
                                                       const float* __restrict__ cn2,
                                                       float* __restrict__ part) {
  __shared__ unsigned char As[2 * 256 * 128], Bs[2 * 256 * 128];  // 64 + 64 KiB
  const int tid = threadIdx.x, lane = tid & 63, wave = tid >> 6;
  const int wm = wave >> 2, wn = wave & 3;       // 2M x 4N
  const int l15 = lane & 15, lhi = lane >> 4;
  int tileY, tileX;
  swz_tile(tileY, tileX);
  const int rowBase = tileY * 256, colBase = tileX * 256;
  const int srow = tid >> 3, ssl = tid & 7;
  const unsigned char* ga = sM8 + (size_t)(rowBase + srow) * D_DIM + ((ssl ^ (srow & 7)) * 16);
  const unsigned char* gb = xte8 + (size_t)(colBase + srow) * D_DIM + ((ssl ^ (srow & 7)) * 16);
  const int aRow0 = wm * 128 + l15;
  const int bRow0 = wn * 64 + l15;
  f32x4 acc[8][4] = {};
  const int nt = D_DIM / 128;                    // 24

  // prologue: stage tile 0 into buffer 0 (8 units)
#pragma unroll
  for (int j = 0; j < 4; ++j) {
    gload16(ga + (size_t)j * 64 * D_DIM, As + j * 8192 + tid * 16);
    gload16(gb + (size_t)j * 64 * D_DIM, Bs + j * 8192 + tid * 16);
  }

  for (int t = 0; t < nt; ++t) {
    const int p = t & 1;
    const unsigned char* Ac = As + p * 32768;
    const unsigned char* Bc = Bs + p * 32768;
    unsigned char* An = As + (p ^ 1) * 32768;
    unsigned char* Bn = Bs + (p ^ 1) * 32768;
    const bool stage = (t + 1 < nt);
    const int k1 = (t + 1) * 128;
    asm volatile("s_waitcnt vmcnt(0)" ::: "memory");   // tile-t units landed
    __builtin_amdgcn_s_barrier();
    __builtin_amdgcn_sched_barrier(0);
    ll2 b16[4];

#define XPH(kp, mq, READB)                                                          \
    {                                                                              \
      ll2 a16[2];                                                                  \
      const int l = (kp) * 4 + lhi;                                                \
      if (READB) {                                                                 \
        _Pragma("unroll") for (int n = 0; n < 4; ++n) {                            \
          const int row = bRow0 + n * 16;                                          \
          b16[n] = *reinterpret_cast<const ll2*>(&Bc[row * 128 + ((l ^ (row & 7)) * 16)]); \
        }                                                                          \
      }                                                                            \
      _Pragma("unroll") for (int i = 0; i < 2; ++i) {                              \
        const int row = aRow0 + ((mq) * 2 + i) * 16;                               \
        a16[i] = *reinterpret_cast<const ll2*>(&Ac[row * 128 + ((l ^ (row & 7)) * 16)]); \
      }                                                                            \
      if ((kp) == 0 && stage) {                                                    \
        gload16(ga + (size_t)(mq) * 64 * D_DIM + k1, An + (mq) * 8192 + tid * 16); \
        gload16(gb + (size_t)(mq) * 64 * D_DIM + k1, Bn + (mq) * 8192 + tid * 16); \
      }                                                                            \
      __builtin_amdgcn_s_barrier();                                                \
      __builtin_amdgcn_sched_barrier(0);                                           \
      __builtin_amdgcn_s_setprio(1);                                               \
      _Pragma("unroll") for (int kk = 0; kk < 2; ++kk)                             \
        _Pragma("unroll") for (int i = 0; i < 2; ++i)                              \
          _Pragma("unroll") for (int n = 0; n < 4; ++n)                            \
            acc[(mq) * 2 + i][n] = __builtin_amdgcn_mfma_f32_16x16x32_fp8_fp8(     \
                a16[i][kk], b16[n][kk], acc[(mq) * 2 + i][n], 0, 0, 0);            \
      __builtin_amdgcn_s_setprio(0);                                               \
      __builtin_amdgcn_s_barrier();                                                \
      __builtin_amdgcn_sched_barrier(0);                                           \
    }

    XPH(0, 0, 1) XPH(0, 1, 0) XPH(0, 2, 0) XPH(0, 3, 0)
    XPH(1, 0, 1) XPH(1, 1, 0) XPH(1, 2, 0) XPH(1, 3, 0)
#undef XPH
  }
  __syncthreads();

  // ---- fused epilogue: kv = exp2(-log2e/10*sqrt(d2)); column partials ----
  float* ylds = reinterpret_cast<float*>(As);                 // [256][12] padded
  float* snlds = ylds + 256 * 12;                             // [256]
  float (*pcol)[11] = reinterpret_cast<float(*)[11]>(Bs);     // [256][11]
  for (int i = tid; i < 2560; i += 512)
    ylds[(i / 10) * 12 + (i % 10)] = Y[(size_t)rowBase * 10 + i];
  if (tid < 256) snlds[tid] = sn2[rowBase + tid];
  for (int i = tid; i < 256 * 11; i += 512) (&pcol[0][0])[i] = 0.f;
  __syncthreads();
#pragma unroll
  for (int ni = 0; ni < 4; ++ni) {
    const float cnv = cn2[colBase + bRow0 + ni * 16];
    float ps[11];
#pragma unroll
    for (int c = 0; c < 11; ++c) ps[c] = 0.f;
#pragma unroll
    for (int m = 0; m < 8; ++m) {
#pragma unroll
      for (int r = 0; r < 4; ++r) {
        const int lrow = wm * 128 + m * 16 + lhi * 4 + r;
        float d2 = snlds[lrow] + cnv - 2.f * acc[m][ni][r];
        float kv = exp2f(-0.14426950408889634f * sqrtf(fmaxf(d2, 0.f)));
        ps[10] += kv;
        f32x4 y0 = *reinterpret_cast<const f32x4*>(&ylds[lrow * 12]);
        f32x4 y1 = *reinterpret_cast<const f32x4*>(&ylds[lrow * 12 + 4]);
        float2 y2 = *reinterpret_cast<const float2*>(&ylds[lrow * 12 + 8]);
#pragma unroll
        for (int c = 0; c < 4; ++c) ps[c] += kv * y0[c];
#pragma unroll
        for (int c = 0; c < 4; ++c) ps[4 + c] += kv * y1[c];
        ps[8] += kv * y2.x;
        ps[9] += kv * y2.y;
      }
    }
#pragma unroll
    for (int c = 0; c < 11; ++c) {
      float v = ps[c];
      v += __shfl_xor(v, 16);
      v += __shfl_xor(v, 32);
      if (lane < 16) atomicAdd(&pcol[wn * 64 + ni * 16 + lane][c], v);
    }
  }
  __syncthreads();
  if (tid < 256) {
    int gcol = colBase + tid;
#pragma unroll
    for (int c = 0; c < 11; ++c)
      part[((size_t)tileY * 11 + c) * NTEST + gcol] = pcol[tid][c];
  }
}

// ---------------- final reduce ----------------
__global__ void k_reduce(const float* __restrict__ part, float* __restrict__ out) {
  int t = blockIdx.x * blockDim.x + threadIdx.x;
  float num[10] = {0, 0, 0, 0, 0, 0, 0, 0, 0, 0};
  float den = 0.f;
  for (int it = 0; it < NTRAIN / 256; ++it) {
    const float* p = part + (size_t)it * 11 * NTEST + t;
#pragma unroll
    for (int c = 0; c < 10; ++c) num[c] += p[(size_t)c * NTEST];
    den += p[(size_t)10 * NTEST];
  }
  float inv = 1.f / den;
#pragma unroll
  for (int c = 0; c < 10; ++c) out[(size_t)t * 10 + c] = num[c] * inv;
}

extern "C" void kernel_launch(void* const* d_in, const int* in_sizes, int n_in,
                              void* d_out, int out_size, void* d_ws, size_t ws_size,
                              hipStream_t stream) {
  const float* x_train = (const float*)d_in[0];
  const float* y_train = (const float*)d_in[1];
  const float* x_test  = (const float*)d_in[2];
  const float* M       = (const float*)d_in[3];
  float* out = (float*)d_out;

  char* ws = (char*)d_ws;
  unsigned short* xtr16 = (unsigned short*)(ws + 0);          // 100663296
  unsigned short* xte16 = (unsigned short*)(ws + 100663296);  // 50331648
  unsigned short* Mt16  = (unsigned short*)(ws + 150994944);  // 18874368
  unsigned char*  sM8   = (unsigned char*)(ws + 169869312);   // 16384*3072 = 50331648
  unsigned char*  xte8  = (unsigned char*)(ws + 220200960);   // 8192*3072  = 25165824
  float* s_n2 = (float*)(ws + 245366784);                     // 65536
  float* c_n2 = (float*)(ws + 245432320);                     // 32768
  float* part = (float*)(ws + 245465088);                     // 64*11*8192*4 = 23068672

  hipMemsetAsync(ws + 245366784, 0, 98304, stream);  // s_n2 + c_n2

  k_convert<<<2048, 256, 0, stream>>>(x_train, xtr16, (long)NTRAIN * D_DIM / 4);
  k_convert<<<2048, 256, 0, stream>>>(x_test, xte16, (long)NTEST * D_DIM / 4);
  k_convert8<<<1024, 256, 0, stream>>>(x_test, xte8, (long)NTEST * D_DIM / 8);
  k_transpose_bf16<<<dim3(96, 96), dim3(32, 8), 0, stream>>>(M, Mt16);
  k_copy4<<<2048, 256, 0, stream>>>((const float4*)M, (float4*)(out + 81920),
                                    (long)D_DIM * D_DIM / 4);

  k_gemm_xm<true><<<dim3(24, 128), 512, 0, stream>>>(xtr16, Mt16, x_train, sM8, s_n2);
  k_gemm_xm<false><<<dim3(24, 64), 512, 0, stream>>>(xte16, Mt16, x_test, nullptr, c_n2);

  // cross: 256x256 tiles -> grid (8192/256, 16384/256)
  k_gemm_cross<<<dim3(32, 64), 512, 0, stream>>>(sM8, xte8, y_train, s_n2, c_n2, part);
  k_reduce<<<32, 256, 0, stream>>>(part, out);
}

// Round 16
// 1425.529 us; speedup vs baseline: 1.6060x; 1.6060x over previous
//
#include <hip/hip_runtime.h>
#include <hip/hip_bf16.h>

#define D_DIM 3072
#define NTRAIN 16384
#define NTEST 8192

typedef __attribute__((ext_vector_type(8))) short short8;
typedef __attribute__((ext_vector_type(4))) float f32x4;
typedef __attribute__((ext_vector_type(2))) long long ll2;

__device__ __forceinline__ unsigned short f2bf(float f) {
  union { float f; unsigned u; } x; x.f = f;
  unsigned r = x.u + 0x7FFFu + ((x.u >> 16) & 1u);
  return (unsigned short)(r >> 16);
}

__device__ __forceinline__ float bf2f(unsigned short b) {
  union { unsigned u; float f; } x; x.u = ((unsigned)b) << 16;
  return x.f;
}

__device__ __forceinline__ void gload16(const void* g, void* l) {
  __builtin_amdgcn_global_load_lds(
      (const __attribute__((address_space(1))) void*)g,
      (__attribute__((address_space(3))) void*)l, 16, 0, 0);
}

// T1: bijective chunked XCD swizzle + 8x8 supertile ordering (gx%8==0, gy%8==0).
__device__ __forceinline__ void swz_tile(int& tileY, int& tileX) {
  const int gx = gridDim.x, gy = gridDim.y;
  const int L = blockIdx.y * gx + blockIdx.x;
  const int q = (gx * gy) >> 3;
  const int s = (L & 7) * q + (L >> 3);
  const int sid = s >> 6;
  const int t = s & 63;
  const int scols = gx >> 3;
  const int sy = sid / scols, sx = sid - sy * scols;
  tileY = sy * 8 + (t >> 3);
  tileX = sx * 8 + (t & 7);
}

// ---------------- pass 0 ----------------
__global__ void k_convert(const float* __restrict__ in, unsigned short* __restrict__ out, long n4) {
  long i = (long)blockIdx.x * blockDim.x + threadIdx.x;
  long stride = (long)gridDim.x * blockDim.x;
  for (; i < n4; i += stride) {
    float4 v = reinterpret_cast<const float4*>(in)[i];
    ushort4 o;
    o.x = f2bf(v.x); o.y = f2bf(v.y); o.z = f2bf(v.z); o.w = f2bf(v.w);
    reinterpret_cast<ushort4*>(out)[i] = o;
  }
}

// f32 -> fp8 e4m3 (OCP, saturating), 8 elems/thread-iter
__global__ void k_convert8(const float* __restrict__ in, unsigned char* __restrict__ out, long n8) {
  long i = (long)blockIdx.x * blockDim.x + threadIdx.x;
  long stride = (long)gridDim.x * blockDim.x;
  for (; i < n8; i += stride) {
    float4 a = reinterpret_cast<const float4*>(in)[i * 2];
    float4 b = reinterpret_cast<const float4*>(in)[i * 2 + 1];
    int w0 = __builtin_amdgcn_cvt_pk_fp8_f32(a.x, a.y, 0, false);
    w0 = __builtin_amdgcn_cvt_pk_fp8_f32(a.z, a.w, w0, true);
    int w1 = __builtin_amdgcn_cvt_pk_fp8_f32(b.x, b.y, 0, false);
    w1 = __builtin_amdgcn_cvt_pk_fp8_f32(b.z, b.w, w1, true);
    reinterpret_cast<int2*>(out)[i] = make_int2(w0, w1);
  }
}

__global__ void k_copy4(const float4* __restrict__ in, float4* __restrict__ out, long n4) {
  long i = (long)blockIdx.x * blockDim.x + threadIdx.x;
  long stride = (long)gridDim.x * blockDim.x;
  for (; i < n4; i += stride) out[i] = in[i];
}

__global__ void k_transpose_bf16(const float* __restrict__ M, unsigned short* __restrict__ Mt) {
  __shared__ float t[32][33];
  int bx = blockIdx.x * 32, by = blockIdx.y * 32;
  int tx = threadIdx.x, ty = threadIdx.y;
#pragma unroll
  for (int i = 0; i < 32; i += 8)
    t[ty + i][tx] = M[(size_t)(by + ty + i) * D_DIM + bx + tx];
  __syncthreads();
#pragma unroll
  for (int i = 0; i < 32; i += 8)
    Mt[(size_t)(bx + ty + i) * D_DIM + by + tx] = f2bf(t[tx][ty + i]);
}

// ------- R6 xm main loop: 512 threads, 32x64 wave tiles, bf16, T2 swizzle -------
__device__ __forceinline__ void mainloopXM(const unsigned short* __restrict__ A,
                                           const unsigned short* __restrict__ B,
                                           int K, int rowBase, int colBase,
                                           unsigned short* As, unsigned short* Bs,
                                           f32x4 acc[2][4]) {
  const int tid = threadIdx.x;
  const int lane = tid & 63;
  const int wave = tid >> 6;
  const int wm = wave >> 1, wn = wave & 1;
  const int sr = tid >> 3;
  const int ssl = tid & 7;
  const int scol = ((ssl ^ (sr & 7)) * 8);
  const unsigned short* ga = A + (size_t)(rowBase + sr) * K + scol;
  const unsigned short* gb = B + (size_t)(colBase + sr) * K + scol;
  const int arow = wm * 32 + (lane & 15);
  const int brow = wn * 64 + (lane & 15);
  const int lsw = lane & 7;
  const int lhi = lane >> 4;
  for (int k0 = 0; k0 < K; k0 += 64) {
#pragma unroll
    for (int c = 0; c < 2; ++c) {
      gload16(ga + (size_t)c * 64 * K + k0, As + c * 4096 + tid * 8);
      gload16(gb + (size_t)c * 64 * K + k0, Bs + c * 4096 + tid * 8);
    }
    __syncthreads();
#pragma unroll
    for (int kk = 0; kk < 2; ++kk) {
      short8 af[2], bfr[4];
      const int sl = ((lhi + kk * 4) ^ lsw) * 8;
#pragma unroll
      for (int i = 0; i < 2; ++i)
        af[i] = *reinterpret_cast<const short8*>(&As[(arow + i * 16) * 64 + sl]);
#pragma unroll
      for (int j = 0; j < 4; ++j)
        bfr[j] = *reinterpret_cast<const short8*>(&Bs[(brow + j * 16) * 64 + sl]);
#pragma unroll
      for (int i = 0; i < 2; ++i)
#pragma unroll
        for (int j = 0; j < 4; ++j)
          acc[i][j] = __builtin_amdgcn_mfma_f32_16x16x32_bf16(af[i], bfr[j], acc[i][j], 0, 0, 0);
    }
    __syncthreads();
  }
}

// ---- GEMM1: X @ M (R6-exact). Epilogue: norm2 (+ optional fp8 sM write) ----
template <bool WRITE_SM>
__global__ __launch_bounds__(512, 4) void k_gemm_xm(const unsigned short* __restrict__ A,
                                                    const unsigned short* __restrict__ Bt,
                                                    const float* __restrict__ Xf,
                                                    unsigned char* __restrict__ smOut,
                                                    float* __restrict__ norm) {
  __shared__ unsigned short As[128 * 64], Bs[128 * 64];
  int tileY, tileX;
  swz_tile(tileY, tileX);
  const int rowBase = tileY * 128, colBase = tileX * 128;
  f32x4 acc[2][4] = {};
  mainloopXM(A, Bt, D_DIM, rowBase, colBase, As, Bs, acc);
  const int tid = threadIdx.x, lane = tid & 63;
  const int wave = tid >> 6;
  const int wm = wave >> 1, wn = wave & 1;
  const int r0 = wm * 32 + (lane >> 4) * 4;
  const int c0 = colBase + wn * 64 + (lane & 15);
#pragma unroll
  for (int mi = 0; mi < 2; ++mi) {
#pragma unroll
    for (int r = 0; r < 4; ++r) {
      const size_t grow = rowBase + r0 + mi * 16 + r;
      float v = 0.f;
#pragma unroll
      for (int ni = 0; ni < 4; ++ni) {
        float a = acc[mi][ni][r];
        int gcol = c0 + ni * 16;
        v += a * Xf[grow * D_DIM + gcol];
        if (WRITE_SM) {
          int p = __builtin_amdgcn_cvt_pk_fp8_f32(a, a, 0, false);
          smOut[grow * D_DIM + gcol] = (unsigned char)(p & 0xFF);
        }
      }
      v += __shfl_xor(v, 1); v += __shfl_xor(v, 2);
      v += __shfl_xor(v, 4); v += __shfl_xor(v, 8);
      if ((lane & 15) == 0) atomicAdd(&norm[grow], v);
    }
  }
}

// ======== GEMM2: fp8 e4m3, 256x256 tile, BK=128, m201 8-phase, STORE-ONLY epilogue ========
// 8 waves (2M x 4N), wave tile 128x64, acc[8][4]=128 regs (AGPR-able since the
// epilogue is a plain store — no ps[11]/ylds pressure, the R10/R15 spill trigger).
// Per phase (kp,mq): 2 A b128 (+4 B b128 at mq==0) ; 2 stage gloads for t+1 at
// kp==0 ; barrier ; setprio+16 MFMA+setprio ; barrier. Tile start: vmcnt(0)+barrier
// (units had >=4 phases of flight). 128-B rows, slot = l ^ (row&7) (0-conflict).
// Output: kv = exp2(-log2e/10*sqrt(d2)) stored bf16 to S[NTRAIN][4096] (half of NTEST).
__global__ __launch_bounds__(512, 2) void k_gemm_cross(const unsigned char* __restrict__ sM8,
                                                       const unsigned char* __restrict__ xte8h,
                                                       const float* __restrict__ sn2,
                                                       const float* __restrict__ cn2h,
                                                       unsigned short* __restrict__ S) {
  __shared__ unsigned char As[2 * 256 * 128], Bs[2 * 256 * 128];  // 64 + 64 KiB
  const int tid = threadIdx.x, lane = tid & 63, wave = tid >> 6;
  const int wm = wave >> 2, wn = wave & 3;       // 2M x 4N
  const int l15 = lane & 15, lhi = lane >> 4;
  int tileY, tileX;
  swz_tile(tileY, tileX);
  const int rowBase = tileY * 256, colBase = tileX * 256;
  const int srow = tid >> 3, ssl = tid & 7;
  const unsigned char* ga = sM8 + (size_t)(rowBase + srow) * D_DIM + ((ssl ^ (srow & 7)) * 16);
  const unsigned char* gb = xte8h + (size_t)(colBase + srow) * D_DIM + ((ssl ^ (srow & 7)) * 16);
  const int aRow0 = wm * 128 + l15;
  const int bRow0 = wn * 64 + l15;
  f32x4 acc[8][4] = {};
  const int nt = D_DIM / 128;                    // 24

  // prologue: stage tile 0 into buffer 0 (8 units)
#pragma unroll
  for (int j = 0; j < 4; ++j) {
    gload16(ga + (size_t)j * 64 * D_DIM, As + j * 8192 + tid * 16);
    gload16(gb + (size_t)j * 64 * D_DIM, Bs + j * 8192 + tid * 16);
  }

  for (int t = 0; t < nt; ++t) {
    const int p = t & 1;
    const unsigned char* Ac = As + p * 32768;
    const unsigned char* Bc = Bs + p * 32768;
    unsigned char* An = As + (p ^ 1) * 32768;
    unsigned char* Bn = Bs + (p ^ 1) * 32768;
    const bool stage = (t + 1 < nt);
    const int k1 = (t + 1) * 128;
    asm volatile("s_waitcnt vmcnt(0)" ::: "memory");   // tile-t units landed
    __builtin_amdgcn_s_barrier();
    __builtin_amdgcn_sched_barrier(0);
    ll2 b16[4];

#define XPH(kp, mq, READB)                                                          \
    {                                                                              \
      ll2 a16[2];                                                                  \
      const int l = (kp) * 4 + lhi;                                                \
      if (READB) {                                                                 \
        _Pragma("unroll") for (int n = 0; n < 4; ++n) {                            \
          const int row = bRow0 + n * 16;                                          \
          b16[n] = *reinterpret_cast<const ll2*>(&Bc[row * 128 + ((l ^ (row & 7)) * 16)]); \
        }                                                                          \
      }                                                                            \
      _Pragma("unroll") for (int i = 0; i < 2; ++i) {                              \
        const int row = aRow0 + ((mq) * 2 + i) * 16;                               \
        a16[i] = *reinterpret_cast<const ll2*>(&Ac[row * 128 + ((l ^ (row & 7)) * 16)]); \
      }                                                                            \
      if ((kp) == 0 && stage) {                                                    \
        gload16(ga + (size_t)(mq) * 64 * D_DIM + k1, An + (mq) * 8192 + tid * 16); \
        gload16(gb + (size_t)(mq) * 64 * D_DIM + k1, Bn + (mq) * 8192 + tid * 16); \
      }                                                                            \
      __builtin_amdgcn_s_barrier();                                                \
      __builtin_amdgcn_sched_barrier(0);                                           \
      __builtin_amdgcn_s_setprio(1);                                               \
      _Pragma("unroll") for (int kk = 0; kk < 2; ++kk)                             \
        _Pragma("unroll") for (int i = 0; i < 2; ++i)                              \
          _Pragma("unroll") for (int n = 0; n < 4; ++n)                            \
            acc[(mq) * 2 + i][n] = __builtin_amdgcn_mfma_f32_16x16x32_fp8_fp8(     \
                a16[i][kk], b16[n][kk], acc[(mq) * 2 + i][n], 0, 0, 0);            \
      __builtin_amdgcn_s_setprio(0);                                               \
      __builtin_amdgcn_s_barrier();                                                \
      __builtin_amdgcn_sched_barrier(0);                                           \
    }

    XPH(0, 0, 1) XPH(0, 1, 0) XPH(0, 2, 0) XPH(0, 3, 0)
    XPH(1, 0, 1) XPH(1, 1, 0) XPH(1, 2, 0) XPH(1, 3, 0)
#undef XPH
  }
  __syncthreads();

  // ---- STORE-ONLY epilogue: kv -> bf16 S (no reduction, no atomics) ----
  float* snlds = reinterpret_cast<float*>(As);     // [256]
  if (tid < 256) snlds[tid] = sn2[rowBase + tid];
  __syncthreads();
  float cn[4];
#pragma unroll
  for (int n = 0; n < 4; ++n) cn[n] = cn2h[colBase + bRow0 + n * 16];
#pragma unroll
  for (int m = 0; m < 8; ++m) {
#pragma unroll
    for (int r = 0; r < 4; ++r) {
      const int lrow = wm * 128 + m * 16 + lhi * 4 + r;
      const float sn = snlds[lrow];
      const size_t grow = rowBase + lrow;
#pragma unroll
      for (int n = 0; n < 4; ++n) {
        float d2 = sn + cn[n] - 2.f * acc[m][n][r];
        float kv = exp2f(-0.14426950408889634f * sqrtf(fmaxf(d2, 0.f)));
        S[grow * 4096 + colBase + bRow0 + n * 16] = f2bf(kv);
      }
    }
  }
}

// ---- k_out: column-wise weighted reduction of one half of S -> part ----
__global__ __launch_bounds__(256) void k_out(const unsigned short* __restrict__ S,
                                             const float* __restrict__ Y,
                                             float* __restrict__ part, int halfBase) {
  __shared__ float ylds[256 * 10];
  const int tid = threadIdx.x;
  const int sBase = blockIdx.y * 256;
  const int tloc = blockIdx.x * 256 + tid;       // 0..4095
  const int tglob = halfBase + tloc;
  for (int i = tid; i < 2560; i += 256) ylds[i] = Y[(size_t)sBase * 10 + i];
  __syncthreads();
  float num[10] = {0, 0, 0, 0, 0, 0, 0, 0, 0, 0};
  float den = 0.f;
  for (int s = 0; s < 256; ++s) {
    float kv = bf2f(S[(size_t)(sBase + s) * 4096 + tloc]);
    const float* yr = &ylds[s * 10];
#pragma unroll
    for (int c = 0; c < 10; ++c) num[c] += kv * yr[c];
    den += kv;
  }
#pragma unroll
  for (int c = 0; c < 10; ++c)
    part[((size_t)blockIdx.y * 11 + c) * NTEST + tglob] = num[c];
  part[((size_t)blockIdx.y * 11 + 10) * NTEST + tglob] = den;
}

// ---------------- final reduce ----------------
__global__ void k_reduce(const float* __restrict__ part, float* __restrict__ out) {
  int t = blockIdx.x * blockDim.x + threadIdx.x;
  float num[10] = {0, 0, 0, 0, 0, 0, 0, 0, 0, 0};
  float den = 0.f;
  for (int it = 0; it < NTRAIN / 256; ++it) {
    const float* p = part + (size_t)it * 11 * NTEST + t;
#pragma unroll
    for (int c = 0; c < 10; ++c) num[c] += p[(size_t)c * NTEST];
    den += p[(size_t)10 * NTEST];
  }
  float inv = 1.f / den;
#pragma unroll
  for (int c = 0; c < 10; ++c) out[(size_t)t * 10 + c] = num[c] * inv;
}

extern "C" void kernel_launch(void* const* d_in, const int* in_sizes, int n_in,
                              void* d_out, int out_size, void* d_ws, size_t ws_size,
                              hipStream_t stream) {
  const float* x_train = (const float*)d_in[0];
  const float* y_train = (const float*)d_in[1];
  const float* x_test  = (const float*)d_in[2];
  const float* M       = (const float*)d_in[3];
  float* out = (float*)d_out;

  char* ws = (char*)d_ws;
  // Phase-1 region [0,169869312): xtr16/xte16/Mt16 — dead after the xm GEMMs,
  // then reused as S (134217728 B) during the cross halves.
  unsigned short* xtr16 = (unsigned short*)(ws + 0);          // 100663296
  unsigned short* xte16 = (unsigned short*)(ws + 100663296);  // 50331648
  unsigned short* Mt16  = (unsigned short*)(ws + 150994944);  // 18874368
  unsigned short* S     = (unsigned short*)(ws + 0);          // 134217728 (aliases the above)
  unsigned char*  sM8   = (unsigned char*)(ws + 169869312);   // 50331648
  unsigned char*  xte8  = (unsigned char*)(ws + 220200960);   // 25165824
  float* s_n2 = (float*)(ws + 245366784);                     // 65536
  float* c_n2 = (float*)(ws + 245432320);                     // 32768
  float* part = (float*)(ws + 245465088);                     // 64*11*8192*4 = 23068672

  hipMemsetAsync(ws + 245366784, 0, 98304, stream);  // s_n2 + c_n2

  k_convert<<<2048, 256, 0, stream>>>(x_train, xtr16, (long)NTRAIN * D_DIM / 4);
  k_convert<<<2048, 256, 0, stream>>>(x_test, xte16, (long)NTEST * D_DIM / 4);
  k_convert8<<<1024, 256, 0, stream>>>(x_test, xte8, (long)NTEST * D_DIM / 8);
  k_transpose_bf16<<<dim3(96, 96), dim3(32, 8), 0, stream>>>(M, Mt16);
  k_copy4<<<2048, 256, 0, stream>>>((const float4*)M, (float4*)(out + 81920),
                                    (long)D_DIM * D_DIM / 4);

  k_gemm_xm<true><<<dim3(24, 128), 512, 0, stream>>>(xtr16, Mt16, x_train, sM8, s_n2);
  k_gemm_xm<false><<<dim3(24, 64), 512, 0, stream>>>(xte16, Mt16, x_test, nullptr, c_n2);

  // cross in two column halves: 256x256 tiles, grid (4096/256, 16384/256)
  for (int h = 0; h < 2; ++h) {
    k_gemm_cross<<<dim3(16, 64), 512, 0, stream>>>(
        sM8, xte8 + (size_t)h * 4096 * D_DIM, s_n2, c_n2 + h * 4096, S);
    k_out<<<dim3(16, 64), 256, 0, stream>>>(S, y_train, part, h * 4096);
  }
  k_reduce<<<32, 256, 0, stream>>>(part, out);
}

// Round 17
// 1365.325 us; speedup vs baseline: 1.6768x; 1.0441x over previous
//
#include <hip/hip_runtime.h>
#include <hip/hip_bf16.h>

#define D_DIM 3072
#define NTRAIN 16384
#define NTEST 8192

typedef __attribute__((ext_vector_type(4))) float f32x4;
typedef __attribute__((ext_vector_type(2))) long long ll2;

__device__ __forceinline__ unsigned short f2bf(float f) {
  union { float f; unsigned u; } x; x.f = f;
  unsigned r = x.u + 0x7FFFu + ((x.u >> 16) & 1u);
  return (unsigned short)(r >> 16);
}

__device__ __forceinline__ float bf2f(unsigned short b) {
  union { unsigned u; float f; } x; x.u = ((unsigned)b) << 16;
  return x.f;
}

__device__ __forceinline__ void gload16(const void* g, void* l) {
  __builtin_amdgcn_global_load_lds(
      (const __attribute__((address_space(1))) void*)g,
      (__attribute__((address_space(3))) void*)l, 16, 0, 0);
}

// T1a: bijective chunked XCD swizzle + 8x8 supertile (needs gx%8==0, gy%8==0).
__device__ __forceinline__ void swz_tile(int& tileY, int& tileX) {
  const int gx = gridDim.x, gy = gridDim.y;
  const int L = blockIdx.y * gx + blockIdx.x;
  const int q = (gx * gy) >> 3;
  const int s = (L & 7) * q + (L >> 3);
  const int sid = s >> 6;
  const int t = s & 63;
  const int scols = gx >> 3;
  const int sy = sid / scols, sx = sid - sy * scols;
  tileY = sy * 8 + (t >> 3);
  tileX = sx * 8 + (t & 7);
}

// T1b: plain bijective chunked swizzle (needs nwg%8==0 only; row-contiguous chunks).
__device__ __forceinline__ void swz_lin(int& tileY, int& tileX) {
  const int gx = gridDim.x;
  const int nwg = gx * gridDim.y;
  const int L = blockIdx.y * gx + blockIdx.x;
  const int s = (L & 7) * (nwg >> 3) + (L >> 3);
  tileY = s / gx;
  tileX = s - tileY * gx;
}

// ---------------- pass 0 ----------------
// f32 -> fp8 e4m3 (OCP, saturating), 8 elems/thread-iter
__global__ void k_convert8(const float* __restrict__ in, unsigned char* __restrict__ out, long n8) {
  long i = (long)blockIdx.x * blockDim.x + threadIdx.x;
  long stride = (long)gridDim.x * blockDim.x;
  for (; i < n8; i += stride) {
    float4 a = reinterpret_cast<const float4*>(in)[i * 2];
    float4 b = reinterpret_cast<const float4*>(in)[i * 2 + 1];
    int w0 = __builtin_amdgcn_cvt_pk_fp8_f32(a.x, a.y, 0, false);
    w0 = __builtin_amdgcn_cvt_pk_fp8_f32(a.z, a.w, w0, true);
    int w1 = __builtin_amdgcn_cvt_pk_fp8_f32(b.x, b.y, 0, false);
    w1 = __builtin_amdgcn_cvt_pk_fp8_f32(b.z, b.w, w1, true);
    reinterpret_cast<int2*>(out)[i] = make_int2(w0, w1);
  }
}

__global__ void k_copy4(const float4* __restrict__ in, float4* __restrict__ out, long n4) {
  long i = (long)blockIdx.x * blockDim.x + threadIdx.x;
  long stride = (long)gridDim.x * blockDim.x;
  for (; i < n4; i += stride) out[i] = in[i];
}

// Mt8[n][k] = fp8(M[k][n])
__global__ void k_transpose_fp8(const float* __restrict__ M, unsigned char* __restrict__ Mt) {
  __shared__ float t[32][33];
  int bx = blockIdx.x * 32, by = blockIdx.y * 32;
  int tx = threadIdx.x, ty = threadIdx.y;
#pragma unroll
  for (int i = 0; i < 32; i += 8)
    t[ty + i][tx] = M[(size_t)(by + ty + i) * D_DIM + bx + tx];
  __syncthreads();
#pragma unroll
  for (int i = 0; i < 32; i += 8) {
    float v = t[tx][ty + i];
    int p = __builtin_amdgcn_cvt_pk_fp8_f32(v, v, 0, false);
    Mt[(size_t)(bx + ty + i) * D_DIM + by + tx] = (unsigned char)(p & 0xFF);
  }
}

// ======== shared 8-phase fp8 mainloop: 256x256 tile, BK=128, m201 schedule ========
// 8 waves (2M x 4N), wave tile 128x64, acc[8][4]=128 regs. LDS 128 KiB dbuf.
// 128-B rows, phys slot = l ^ (row&7) (measured-0-conflict layout).
// Per phase (kp,mq): 2 A b128 (+4 B b128 at mq==0); 2 stage gloads for t+1 at
// kp==0; barrier; setprio + 16 MFMA + setprio; barrier. Tile start: vmcnt(0)
// +barrier (loads had 4-8 phases of flight -> near-free drain).
__device__ __forceinline__ void mainloop8ph(const unsigned char* __restrict__ ga,
                                            const unsigned char* __restrict__ gb,
                                            unsigned char* As, unsigned char* Bs,
                                            int aRow0, int bRow0, int lhi, int tid,
                                            f32x4 acc[8][4]) {
  const int nt = D_DIM / 128;                    // 24
#pragma unroll
  for (int j = 0; j < 4; ++j) {
    gload16(ga + (size_t)j * 64 * D_DIM, As + j * 8192 + tid * 16);
    gload16(gb + (size_t)j * 64 * D_DIM, Bs + j * 8192 + tid * 16);
  }
  for (int t = 0; t < nt; ++t) {
    const int p = t & 1;
    const unsigned char* Ac = As + p * 32768;
    const unsigned char* Bc = Bs + p * 32768;
    unsigned char* An = As + (p ^ 1) * 32768;
    unsigned char* Bn = Bs + (p ^ 1) * 32768;
    const bool stage = (t + 1 < nt);
    const int k1 = (t + 1) * 128;
    asm volatile("s_waitcnt vmcnt(0)" ::: "memory");   // tile-t units landed
    __builtin_amdgcn_s_barrier();
    __builtin_amdgcn_sched_barrier(0);
    ll2 b16[4];

#define XPH(kp, mq, READB)                                                          \
    {                                                                              \
      ll2 a16[2];                                                                  \
      const int l = (kp) * 4 + lhi;                                                \
      if (READB) {                                                                 \
        _Pragma("unroll") for (int n = 0; n < 4; ++n) {                            \
          const int row = bRow0 + n * 16;                                          \
          b16[n] = *reinterpret_cast<const ll2*>(&Bc[row * 128 + ((l ^ (row & 7)) * 16)]); \
        }                                                                          \
      }                                                                            \
      _Pragma("unroll") for (int i = 0; i < 2; ++i) {                              \
        const int row = aRow0 + ((mq) * 2 + i) * 16;                               \
        a16[i] = *reinterpret_cast<const ll2*>(&Ac[row * 128 + ((l ^ (row & 7)) * 16)]); \
      }                                                                            \
      if ((kp) == 0 && stage) {                                                    \
        gload16(ga + (size_t)(mq) * 64 * D_DIM + k1, An + (mq) * 8192 + tid * 16); \
        gload16(gb + (size_t)(mq) * 64 * D_DIM + k1, Bn + (mq) * 8192 + tid * 16); \
      }                                                                            \
      __builtin_amdgcn_s_barrier();                                                \
      __builtin_amdgcn_sched_barrier(0);                                           \
      __builtin_amdgcn_s_setprio(1);                                               \
      _Pragma("unroll") for (int kk = 0; kk < 2; ++kk)                             \
        _Pragma("unroll") for (int i = 0; i < 2; ++i)                              \
          _Pragma("unroll") for (int n = 0; n < 4; ++n)                            \
            acc[(mq) * 2 + i][n] = __builtin_amdgcn_mfma_f32_16x16x32_fp8_fp8(     \
                a16[i][kk], b16[n][kk], acc[(mq) * 2 + i][n], 0, 0, 0);            \
      __builtin_amdgcn_s_setprio(0);                                               \
      __builtin_amdgcn_s_barrier();                                                \
      __builtin_amdgcn_sched_barrier(0);                                           \
    }

    XPH(0, 0, 1) XPH(0, 1, 0) XPH(0, 2, 0) XPH(0, 3, 0)
    XPH(1, 0, 1) XPH(1, 1, 0) XPH(1, 2, 0) XPH(1, 3, 0)
#undef XPH
  }
}

// ---- GEMM1: X @ M, fp8, 8-phase. Epilogue: norm2 dot vs f32 X (+ optional sM8) ----
template <bool WRITE_SM>
__global__ __launch_bounds__(512, 2) void k_gemm_xm8(const unsigned char* __restrict__ X8,
                                                     const unsigned char* __restrict__ Mt8,
                                                     const float* __restrict__ Xf,
                                                     unsigned char* __restrict__ smOut,
                                                     float* __restrict__ norm) {
  __shared__ unsigned char As[2 * 256 * 128], Bs[2 * 256 * 128];
  const int tid = threadIdx.x, lane = tid & 63, wave = tid >> 6;
  const int wm = wave >> 2, wn = wave & 3;       // 2M x 4N
  const int l15 = lane & 15, lhi = lane >> 4;
  int tileY, tileX;
  swz_lin(tileY, tileX);                          // gx=12 not supertile-compatible
  const int rowBase = tileY * 256, colBase = tileX * 256;
  const int srow = tid >> 3, ssl = tid & 7;
  const unsigned char* ga = X8 + (size_t)(rowBase + srow) * D_DIM + ((ssl ^ (srow & 7)) * 16);
  const unsigned char* gb = Mt8 + (size_t)(colBase + srow) * D_DIM + ((ssl ^ (srow & 7)) * 16);
  f32x4 acc[8][4] = {};
  mainloop8ph(ga, gb, As, Bs, wm * 128 + l15, wn * 64 + l15, lhi, tid, acc);
  __syncthreads();

  // scalar-only epilogue (no arrays -> no spill): row-dot with f32 X + shfl + atomic
  const int c0 = colBase + wn * 64 + l15;
#pragma unroll
  for (int m = 0; m < 8; ++m) {
#pragma unroll
    for (int r = 0; r < 4; ++r) {
      const size_t grow = rowBase + wm * 128 + m * 16 + lhi * 4 + r;
      float v = 0.f;
#pragma unroll
      for (int n = 0; n < 4; ++n) {
        float a = acc[m][n][r];
        const int gcol = c0 + n * 16;
        v += a * Xf[grow * D_DIM + gcol];
        if (WRITE_SM) {
          int pk = __builtin_amdgcn_cvt_pk_fp8_f32(a, a, 0, false);
          smOut[grow * D_DIM + gcol] = (unsigned char)(pk & 0xFF);
        }
      }
      v += __shfl_xor(v, 1); v += __shfl_xor(v, 2);
      v += __shfl_xor(v, 4); v += __shfl_xor(v, 8);
      if ((lane & 15) == 0) atomicAdd(&norm[grow], v);
    }
  }
}

// ---- GEMM2 (R16-exact): fp8 8-phase, STORE-ONLY epilogue -> bf16 S half ----
__global__ __launch_bounds__(512, 2) void k_gemm_cross(const unsigned char* __restrict__ sM8,
                                                       const unsigned char* __restrict__ xte8h,
                                                       const float* __restrict__ sn2,
                                                       const float* __restrict__ cn2h,
                                                       unsigned short* __restrict__ S) {
  __shared__ unsigned char As[2 * 256 * 128], Bs[2 * 256 * 128];
  const int tid = threadIdx.x, lane = tid & 63, wave = tid >> 6;
  const int wm = wave >> 2, wn = wave & 3;
  const int l15 = lane & 15, lhi = lane >> 4;
  int tileY, tileX;
  swz_tile(tileY, tileX);
  const int rowBase = tileY * 256, colBase = tileX * 256;
  const int srow = tid >> 3, ssl = tid & 7;
  const unsigned char* ga = sM8 + (size_t)(rowBase + srow) * D_DIM + ((ssl ^ (srow & 7)) * 16);
  const unsigned char* gb = xte8h + (size_t)(colBase + srow) * D_DIM + ((ssl ^ (srow & 7)) * 16);
  const int bRow0 = wn * 64 + l15;
  f32x4 acc[8][4] = {};
  mainloop8ph(ga, gb, As, Bs, wm * 128 + l15, bRow0, lhi, tid, acc);
  __syncthreads();

  float* snlds = reinterpret_cast<float*>(As);     // [256]
  if (tid < 256) snlds[tid] = sn2[rowBase + tid];
  __syncthreads();
  float cn[4];
#pragma unroll
  for (int n = 0; n < 4; ++n) cn[n] = cn2h[colBase + bRow0 + n * 16];
#pragma unroll
  for (int m = 0; m < 8; ++m) {
#pragma unroll
    for (int r = 0; r < 4; ++r) {
      const int lrow = wm * 128 + m * 16 + lhi * 4 + r;
      const float sn = snlds[lrow];
      const size_t grow = rowBase + lrow;
#pragma unroll
      for (int n = 0; n < 4; ++n) {
        float d2 = sn + cn[n] - 2.f * acc[m][n][r];
        float kv = exp2f(-0.14426950408889634f * sqrtf(fmaxf(d2, 0.f)));
        S[grow * 4096 + colBase + bRow0 + n * 16] = f2bf(kv);
      }
    }
  }
}

// ---- k_out: column-wise weighted reduction of one half of S -> part ----
__global__ __launch_bounds__(256) void k_out(const unsigned short* __restrict__ S,
                                             const float* __restrict__ Y,
                                             float* __restrict__ part, int halfBase) {
  __shared__ float ylds[256 * 10];
  const int tid = threadIdx.x;
  const int sBase = blockIdx.y * 256;
  const int tloc = blockIdx.x * 256 + tid;       // 0..4095
  const int tglob = halfBase + tloc;
  for (int i = tid; i < 2560; i += 256) ylds[i] = Y[(size_t)sBase * 10 + i];
  __syncthreads();
  float num[10] = {0, 0, 0, 0, 0, 0, 0, 0, 0, 0};
  float den = 0.f;
  for (int s = 0; s < 256; ++s) {
    float kv = bf2f(S[(size_t)(sBase + s) * 4096 + tloc]);
    const float* yr = &ylds[s * 10];
#pragma unroll
    for (int c = 0; c < 10; ++c) num[c] += kv * yr[c];
    den += kv;
  }
#pragma unroll
  for (int c = 0; c < 10; ++c)
    part[((size_t)blockIdx.y * 11 + c) * NTEST + tglob] = num[c];
  part[((size_t)blockIdx.y * 11 + 10) * NTEST + tglob] = den;
}

// ---------------- final reduce ----------------
__global__ void k_reduce(const float* __restrict__ part, float* __restrict__ out) {
  int t = blockIdx.x * blockDim.x + threadIdx.x;
  float num[10] = {0, 0, 0, 0, 0, 0, 0, 0, 0, 0};
  float den = 0.f;
  for (int it = 0; it < NTRAIN / 256; ++it) {
    const float* p = part + (size_t)it * 11 * NTEST + t;
#pragma unroll
    for (int c = 0; c < 10; ++c) num[c] += p[(size_t)c * NTEST];
    den += p[(size_t)10 * NTEST];
  }
  float inv = 1.f / den;
#pragma unroll
  for (int c = 0; c < 10; ++c) out[(size_t)t * 10 + c] = num[c] * inv;
}

extern "C" void kernel_launch(void* const* d_in, const int* in_sizes, int n_in,
                              void* d_out, int out_size, void* d_ws, size_t ws_size,
                              hipStream_t stream) {
  const float* x_train = (const float*)d_in[0];
  const float* y_train = (const float*)d_in[1];
  const float* x_test  = (const float*)d_in[2];
  const float* M       = (const float*)d_in[3];
  float* out = (float*)d_out;

  char* ws = (char*)d_ws;
  unsigned char*  xtr8 = (unsigned char*)(ws + 0);            // 16384*3072 = 50331648
  unsigned char*  xte8 = (unsigned char*)(ws + 50331648);     // 8192*3072  = 25165824
  unsigned char*  Mt8  = (unsigned char*)(ws + 75497472);     // 3072*3072  = 9437184
  unsigned char*  sM8  = (unsigned char*)(ws + 84934656);     // 50331648
  float* s_n2 = (float*)(ws + 135266304);                     // 65536
  float* c_n2 = (float*)(ws + 135331840);                     // 32768
  float* part = (float*)(ws + 135364608);                     // 64*11*8192*4 = 23068672
  unsigned short* S = (unsigned short*)(ws + 158433280);      // 16384*4096*2 = 134217728

  hipMemsetAsync(ws + 135266304, 0, 98304, stream);  // s_n2 + c_n2

  k_convert8<<<1024, 256, 0, stream>>>(x_train, xtr8, (long)NTRAIN * D_DIM / 8);
  k_convert8<<<1024, 256, 0, stream>>>(x_test, xte8, (long)NTEST * D_DIM / 8);
  k_transpose_fp8<<<dim3(96, 96), dim3(32, 8), 0, stream>>>(M, Mt8);
  k_copy4<<<2048, 256, 0, stream>>>((const float4*)M, (float4*)(out + 81920),
                                    (long)D_DIM * D_DIM / 4);

  // xm: 256x256 tiles. true: grid (3072/256, 16384/256); false: (12, 8192/256)
  k_gemm_xm8<true><<<dim3(12, 64), 512, 0, stream>>>(xtr8, Mt8, x_train, sM8, s_n2);
  k_gemm_xm8<false><<<dim3(12, 32), 512, 0, stream>>>(xte8, Mt8, x_test, nullptr, c_n2);

  // cross in two column halves: 256x256 tiles, grid (4096/256, 16384/256)
  for (int h = 0; h < 2; ++h) {
    k_gemm_cross<<<dim3(16, 64), 512, 0, stream>>>(
        sM8, xte8 + (size_t)h * 4096 * D_DIM, s_n2, c_n2 + h * 4096, S);
    k_out<<<dim3(16, 64), 256, 0, stream>>>(S, y_train, part, h * 4096);
  }
  k_reduce<<<32, 256, 0, stream>>>(part, out);
}

// Round 18
// 1096.585 us; speedup vs baseline: 2.0877x; 1.2451x over previous
//
#include <hip/hip_runtime.h>
#include <hip/hip_bf16.h>

#define D_DIM 3072
#define NTRAIN 16384
#define NTEST 8192

typedef __attribute__((ext_vector_type(4))) float f32x4;
typedef __attribute__((ext_vector_type(4))) int i32x4;
typedef __attribute__((ext_vector_type(8))) int i32x8;

__device__ __forceinline__ unsigned short f2bf(float f) {
  union { float f; unsigned u; } x; x.f = f;
  unsigned r = x.u + 0x7FFFu + ((x.u >> 16) & 1u);
  return (unsigned short)(r >> 16);
}

__device__ __forceinline__ float bf2f(unsigned short b) {
  union { unsigned u; float f; } x; x.u = ((unsigned)b) << 16;
  return x.f;
}

__device__ __forceinline__ i32x8 cmb(i32x4 lo, i32x4 hi) {
  i32x8 r;
  r[0] = lo[0]; r[1] = lo[1]; r[2] = lo[2]; r[3] = lo[3];
  r[4] = hi[0]; r[5] = hi[1]; r[6] = hi[2]; r[7] = hi[3];
  return r;
}

__device__ __forceinline__ void gload16(const void* g, void* l) {
  __builtin_amdgcn_global_load_lds(
      (const __attribute__((address_space(1))) void*)g,
      (__attribute__((address_space(3))) void*)l, 16, 0, 0);
}

// T1a: bijective chunked XCD swizzle + 8x8 supertile (needs gx%8==0, gy%8==0).
__device__ __forceinline__ void swz_tile(int& tileY, int& tileX) {
  const int gx = gridDim.x, gy = gridDim.y;
  const int L = blockIdx.y * gx + blockIdx.x;
  const int q = (gx * gy) >> 3;
  const int s = (L & 7) * q + (L >> 3);
  const int sid = s >> 6;
  const int t = s & 63;
  const int scols = gx >> 3;
  const int sy = sid / scols, sx = sid - sy * scols;
  tileY = sy * 8 + (t >> 3);
  tileX = sx * 8 + (t & 7);
}

// T1b: plain bijective chunked swizzle (needs nwg%8==0 only).
__device__ __forceinline__ void swz_lin(int& tileY, int& tileX) {
  const int gx = gridDim.x;
  const int nwg = gx * gridDim.y;
  const int L = blockIdx.y * gx + blockIdx.x;
  const int s = (L & 7) * (nwg >> 3) + (L >> 3);
  tileY = s / gx;
  tileX = s - tileY * gx;
}

// ---------------- pass 0 ----------------
__global__ void k_convert8(const float* __restrict__ in, unsigned char* __restrict__ out, long n8) {
  long i = (long)blockIdx.x * blockDim.x + threadIdx.x;
  long stride = (long)gridDim.x * blockDim.x;
  for (; i < n8; i += stride) {
    float4 a = reinterpret_cast<const float4*>(in)[i * 2];
    float4 b = reinterpret_cast<const float4*>(in)[i * 2 + 1];
    int w0 = __builtin_amdgcn_cvt_pk_fp8_f32(a.x, a.y, 0, false);
    w0 = __builtin_amdgcn_cvt_pk_fp8_f32(a.z, a.w, w0, true);
    int w1 = __builtin_amdgcn_cvt_pk_fp8_f32(b.x, b.y, 0, false);
    w1 = __builtin_amdgcn_cvt_pk_fp8_f32(b.z, b.w, w1, true);
    reinterpret_cast<int2*>(out)[i] = make_int2(w0, w1);
  }
}

__global__ void k_copy4(const float4* __restrict__ in, float4* __restrict__ out, long n4) {
  long i = (long)blockIdx.x * blockDim.x + threadIdx.x;
  long stride = (long)gridDim.x * blockDim.x;
  for (; i < n4; i += stride) out[i] = in[i];
}

// Mt8[n][k] = fp8(M[k][n])
__global__ void k_transpose_fp8(const float* __restrict__ M, unsigned char* __restrict__ Mt) {
  __shared__ float t[32][33];
  int bx = blockIdx.x * 32, by = blockIdx.y * 32;
  int tx = threadIdx.x, ty = threadIdx.y;
#pragma unroll
  for (int i = 0; i < 32; i += 8)
    t[ty + i][tx] = M[(size_t)(by + ty + i) * D_DIM + bx + tx];
  __syncthreads();
#pragma unroll
  for (int i = 0; i < 32; i += 8) {
    float v = t[tx][ty + i];
    int p = __builtin_amdgcn_cvt_pk_fp8_f32(v, v, 0, false);
    Mt[(size_t)(bx + ty + i) * D_DIM + by + tx] = (unsigned char)(p & 0xFF);
  }
}

// ======== shared 4-phase MX-fp8 mainloop: 256x256 tile, BK=128 ========
// 8 waves (2M x 4N), wave tile 128x64, acc[8][4]=128 regs. LDS 128 KiB dbuf.
// mfma_scale_f32_16x16x128_f8f6f4 with unit scales (E8M0=127 -> x1.0): exact
// fp8 math at 2x the non-scaled rate. Each operand rep = 32B/lane = two b128
// at granules (2*lhi, 2*lhi+1), phys slot = g ^ (row&7) (0-conflict layout).
// Phase q: read A-reps 2q,2q+1 (+all 4 B-reps at q==0); 2 stage gloads for
// t+1; barrier; setprio + 8 scaled MFMA + setprio; barrier.
__device__ __forceinline__ void mainloop4ph(const unsigned char* __restrict__ ga,
                                            const unsigned char* __restrict__ gb,
                                            unsigned char* As, unsigned char* Bs,
                                            int aRow0, int bRow0, int lhi, int tid,
                                            f32x4 acc[8][4]) {
  const int nt = D_DIM / 128;                    // 24
#pragma unroll
  for (int j = 0; j < 4; ++j) {
    gload16(ga + (size_t)j * 64 * D_DIM, As + j * 8192 + tid * 16);
    gload16(gb + (size_t)j * 64 * D_DIM, Bs + j * 8192 + tid * 16);
  }
  const int g0 = 2 * lhi, g1 = 2 * lhi + 1;
  for (int t = 0; t < nt; ++t) {
    const int p = t & 1;
    const unsigned char* Ac = As + p * 32768;
    const unsigned char* Bc = Bs + p * 32768;
    unsigned char* An = As + (p ^ 1) * 32768;
    unsigned char* Bn = Bs + (p ^ 1) * 32768;
    const bool stage = (t + 1 < nt);
    const int k1 = (t + 1) * 128;
    asm volatile("s_waitcnt vmcnt(0)" ::: "memory");   // tile-t units landed
    __builtin_amdgcn_s_barrier();
    __builtin_amdgcn_sched_barrier(0);
    i32x8 b8[4];

#define XPH(q)                                                                      \
    {                                                                              \
      if ((q) == 0) {                                                              \
        _Pragma("unroll") for (int n = 0; n < 4; ++n) {                            \
          const int row = bRow0 + n * 16;                                          \
          const int f = row & 7;                                                   \
          i32x4 lo = *reinterpret_cast<const i32x4*>(&Bc[row * 128 + ((g0 ^ f) * 16)]); \
          i32x4 hi = *reinterpret_cast<const i32x4*>(&Bc[row * 128 + ((g1 ^ f) * 16)]); \
          b8[n] = cmb(lo, hi);                                                     \
        }                                                                          \
      }                                                                            \
      i32x8 a80, a81;                                                              \
      {                                                                            \
        const int r0 = aRow0 + (q) * 32;                                           \
        const int f0 = r0 & 7;                                                     \
        i32x4 lo = *reinterpret_cast<const i32x4*>(&Ac[r0 * 128 + ((g0 ^ f0) * 16)]); \
        i32x4 hi = *reinterpret_cast<const i32x4*>(&Ac[r0 * 128 + ((g1 ^ f0) * 16)]); \
        a80 = cmb(lo, hi);                                                         \
        const int r1 = r0 + 16;                                                    \
        const int f1 = r1 & 7;                                                     \
        lo = *reinterpret_cast<const i32x4*>(&Ac[r1 * 128 + ((g0 ^ f1) * 16)]);    \
        hi = *reinterpret_cast<const i32x4*>(&Ac[r1 * 128 + ((g1 ^ f1) * 16)]);    \
        a81 = cmb(lo, hi);                                                         \
      }                                                                            \
      if (stage) {                                                                 \
        gload16(ga + (size_t)(q) * 64 * D_DIM + k1, An + (q) * 8192 + tid * 16);   \
        gload16(gb + (size_t)(q) * 64 * D_DIM + k1, Bn + (q) * 8192 + tid * 16);   \
      }                                                                            \
      __builtin_amdgcn_s_barrier();                                                \
      __builtin_amdgcn_sched_barrier(0);                                           \
      __builtin_amdgcn_s_setprio(1);                                               \
      _Pragma("unroll") for (int n = 0; n < 4; ++n) {                              \
        acc[(q) * 2][n] = __builtin_amdgcn_mfma_scale_f32_16x16x128_f8f6f4(        \
            a80, b8[n], acc[(q) * 2][n], 0, 0, 0, 127, 0, 127);                    \
        acc[(q) * 2 + 1][n] = __builtin_amdgcn_mfma_scale_f32_16x16x128_f8f6f4(    \
            a81, b8[n], acc[(q) * 2 + 1][n], 0, 0, 0, 127, 0, 127);                \
      }                                                                            \
      __builtin_amdgcn_s_setprio(0);                                               \
      __builtin_amdgcn_s_barrier();                                                \
      __builtin_amdgcn_sched_barrier(0);                                           \
    }

    XPH(0) XPH(1) XPH(2) XPH(3)
#undef XPH
  }
}

// ---- GEMM1: X @ M, MX-fp8. Epilogue: norm2 dot vs f32 X (+ optional sM8) ----
template <bool WRITE_SM>
__global__ __launch_bounds__(512, 2) void k_gemm_xm8(const unsigned char* __restrict__ X8,
                                                     const unsigned char* __restrict__ Mt8,
                                                     const float* __restrict__ Xf,
                                                     unsigned char* __restrict__ smOut,
                                                     float* __restrict__ norm) {
  __shared__ unsigned char As[2 * 256 * 128], Bs[2 * 256 * 128];
  const int tid = threadIdx.x, lane = tid & 63, wave = tid >> 6;
  const int wm = wave >> 2, wn = wave & 3;       // 2M x 4N
  const int l15 = lane & 15, lhi = lane >> 4;
  int tileY, tileX;
  swz_lin(tileY, tileX);
  const int rowBase = tileY * 256, colBase = tileX * 256;
  const int srow = tid >> 3, ssl = tid & 7;
  const unsigned char* ga = X8 + (size_t)(rowBase + srow) * D_DIM + ((ssl ^ (srow & 7)) * 16);
  const unsigned char* gb = Mt8 + (size_t)(colBase + srow) * D_DIM + ((ssl ^ (srow & 7)) * 16);
  f32x4 acc[8][4] = {};
  mainloop4ph(ga, gb, As, Bs, wm * 128 + l15, wn * 64 + l15, lhi, tid, acc);
  __syncthreads();

  const int c0 = colBase + wn * 64 + l15;
#pragma unroll
  for (int m = 0; m < 8; ++m) {
#pragma unroll
    for (int r = 0; r < 4; ++r) {
      const size_t grow = rowBase + wm * 128 + m * 16 + lhi * 4 + r;
      float v = 0.f;
#pragma unroll
      for (int n = 0; n < 4; ++n) {
        float a = acc[m][n][r];
        const int gcol = c0 + n * 16;
        v += a * Xf[grow * D_DIM + gcol];
        if (WRITE_SM) {
          int pk = __builtin_amdgcn_cvt_pk_fp8_f32(a, a, 0, false);
          smOut[grow * D_DIM + gcol] = (unsigned char)(pk & 0xFF);
        }
      }
      v += __shfl_xor(v, 1); v += __shfl_xor(v, 2);
      v += __shfl_xor(v, 4); v += __shfl_xor(v, 8);
      if ((lane & 15) == 0) atomicAdd(&norm[grow], v);
    }
  }
}

// ---- GEMM2: MX-fp8 4-phase, STORE-ONLY epilogue -> bf16 S half ----
__global__ __launch_bounds__(512, 2) void k_gemm_cross(const unsigned char* __restrict__ sM8,
                                                       const unsigned char* __restrict__ xte8h,
                                                       const float* __restrict__ sn2,
                                                       const float* __restrict__ cn2h,
                                                       unsigned short* __restrict__ S) {
  __shared__ unsigned char As[2 * 256 * 128], Bs[2 * 256 * 128];
  const int tid = threadIdx.x, lane = tid & 63, wave = tid >> 6;
  const int wm = wave >> 2, wn = wave & 3;
  const int l15 = lane & 15, lhi = lane >> 4;
  int tileY, tileX;
  swz_tile(tileY, tileX);
  const int rowBase = tileY * 256, colBase = tileX * 256;
  const int srow = tid >> 3, ssl = tid & 7;
  const unsigned char* ga = sM8 + (size_t)(rowBase + srow) * D_DIM + ((ssl ^ (srow & 7)) * 16);
  const unsigned char* gb = xte8h + (size_t)(colBase + srow) * D_DIM + ((ssl ^ (srow & 7)) * 16);
  const int bRow0 = wn * 64 + l15;
  f32x4 acc[8][4] = {};
  mainloop4ph(ga, gb, As, Bs, wm * 128 + l15, bRow0, lhi, tid, acc);
  __syncthreads();

  float* snlds = reinterpret_cast<float*>(As);     // [256]
  if (tid < 256) snlds[tid] = sn2[rowBase + tid];
  __syncthreads();
  float cn[4];
#pragma unroll
  for (int n = 0; n < 4; ++n) cn[n] = cn2h[colBase + bRow0 + n * 16];
#pragma unroll
  for (int m = 0; m < 8; ++m) {
#pragma unroll
    for (int r = 0; r < 4; ++r) {
      const int lrow = wm * 128 + m * 16 + lhi * 4 + r;
      const float sn = snlds[lrow];
      const size_t grow = rowBase + lrow;
#pragma unroll
      for (int n = 0; n < 4; ++n) {
        float d2 = sn + cn[n] - 2.f * acc[m][n][r];
        float kv = exp2f(-0.14426950408889634f * sqrtf(fmaxf(d2, 0.f)));
        S[grow * 4096 + colBase + bRow0 + n * 16] = f2bf(kv);
      }
    }
  }
}

// ---- k_out: column-wise weighted reduction of one half of S -> part ----
__global__ __launch_bounds__(256) void k_out(const unsigned short* __restrict__ S,
                                             const float* __restrict__ Y,
                                             float* __restrict__ part, int halfBase) {
  __shared__ float ylds[256 * 10];
  const int tid = threadIdx.x;
  const int sBase = blockIdx.y * 256;
  const int tloc = blockIdx.x * 256 + tid;       // 0..4095
  const int tglob = halfBase + tloc;
  for (int i = tid; i < 2560; i += 256) ylds[i] = Y[(size_t)sBase * 10 + i];
  __syncthreads();
  float num[10] = {0, 0, 0, 0, 0, 0, 0, 0, 0, 0};
  float den = 0.f;
  for (int s = 0; s < 256; ++s) {
    float kv = bf2f(S[(size_t)(sBase + s) * 4096 + tloc]);
    const float* yr = &ylds[s * 10];
#pragma unroll
    for (int c = 0; c < 10; ++c) num[c] += kv * yr[c];
    den += kv;
  }
#pragma unroll
  for (int c = 0; c < 10; ++c)
    part[((size_t)blockIdx.y * 11 + c) * NTEST + tglob] = num[c];
  part[((size_t)blockIdx.y * 11 + 10) * NTEST + tglob] = den;
}

// ---------------- final reduce ----------------
__global__ void k_reduce(const float* __restrict__ part, float* __restrict__ out) {
  int t = blockIdx.x * blockDim.x + threadIdx.x;
  float num[10] = {0, 0, 0, 0, 0, 0, 0, 0, 0, 0};
  float den = 0.f;
  for (int it = 0; it < NTRAIN / 256; ++it) {
    const float* p = part + (size_t)it * 11 * NTEST + t;
#pragma unroll
    for (int c = 0; c < 10; ++c) num[c] += p[(size_t)c * NTEST];
    den += p[(size_t)10 * NTEST];
  }
  float inv = 1.f / den;
#pragma unroll
  for (int c = 0; c < 10; ++c) out[(size_t)t * 10 + c] = num[c] * inv;
}

extern "C" void kernel_launch(void* const* d_in, const int* in_sizes, int n_in,
                              void* d_out, int out_size, void* d_ws, size_t ws_size,
                              hipStream_t stream) {
  const float* x_train = (const float*)d_in[0];
  const float* y_train = (const float*)d_in[1];
  const float* x_test  = (const float*)d_in[2];
  const float* M       = (const float*)d_in[3];
  float* out = (float*)d_out;

  char* ws = (char*)d_ws;
  unsigned char*  xtr8 = (unsigned char*)(ws + 0);            // 50331648
  unsigned char*  xte8 = (unsigned char*)(ws + 50331648);     // 25165824
  unsigned char*  Mt8  = (unsigned char*)(ws + 75497472);     // 9437184
  unsigned char*  sM8  = (unsigned char*)(ws + 84934656);     // 50331648
  float* s_n2 = (float*)(ws + 135266304);                     // 65536
  float* c_n2 = (float*)(ws + 135331840);                     // 32768
  float* part = (float*)(ws + 135364608);                     // 23068672
  unsigned short* S = (unsigned short*)(ws + 158433280);      // 134217728

  hipMemsetAsync(ws + 135266304, 0, 98304, stream);  // s_n2 + c_n2

  k_convert8<<<1024, 256, 0, stream>>>(x_train, xtr8, (long)NTRAIN * D_DIM / 8);
  k_convert8<<<1024, 256, 0, stream>>>(x_test, xte8, (long)NTEST * D_DIM / 8);
  k_transpose_fp8<<<dim3(96, 96), dim3(32, 8), 0, stream>>>(M, Mt8);
  k_copy4<<<2048, 256, 0, stream>>>((const float4*)M, (float4*)(out + 81920),
                                    (long)D_DIM * D_DIM / 4);

  k_gemm_xm8<true><<<dim3(12, 64), 512, 0, stream>>>(xtr8, Mt8, x_train, sM8, s_n2);
  k_gemm_xm8<false><<<dim3(12, 32), 512, 0, stream>>>(xte8, Mt8, x_test, nullptr, c_n2);

  for (int h = 0; h < 2; ++h) {
    k_gemm_cross<<<dim3(16, 64), 512, 0, stream>>>(
        sM8, xte8 + (size_t)h * 4096 * D_DIM, s_n2, c_n2 + h * 4096, S);
    k_out<<<dim3(16, 64), 256, 0, stream>>>(S, y_train, part, h * 4096);
  }
  k_reduce<<<32, 256, 0, stream>>>(part, out);
}

// Round 19
// 1074.960 us; speedup vs baseline: 2.1297x; 1.0201x over previous
//
#include <hip/hip_runtime.h>
#include <hip/hip_bf16.h>

#define D_DIM 3072
#define NTRAIN 16384
#define NTEST 8192

typedef __attribute__((ext_vector_type(4))) float f32x4;
typedef __attribute__((ext_vector_type(4))) int i32x4;
typedef __attribute__((ext_vector_type(8))) int i32x8;

__device__ __forceinline__ unsigned short f2bf(float f) {
  union { float f; unsigned u; } x; x.f = f;
  unsigned r = x.u + 0x7FFFu + ((x.u >> 16) & 1u);
  return (unsigned short)(r >> 16);
}

__device__ __forceinline__ float bf2f(unsigned short b) {
  union { unsigned u; float f; } x; x.u = ((unsigned)b) << 16;
  return x.f;
}

__device__ __forceinline__ i32x8 cmb(i32x4 lo, i32x4 hi) {
  i32x8 r;
  r[0] = lo[0]; r[1] = lo[1]; r[2] = lo[2]; r[3] = lo[3];
  r[4] = hi[0]; r[5] = hi[1]; r[6] = hi[2]; r[7] = hi[3];
  return r;
}

__device__ __forceinline__ void gload16(const void* g, void* l) {
  __builtin_amdgcn_global_load_lds(
      (const __attribute__((address_space(1))) void*)g,
      (__attribute__((address_space(3))) void*)l, 16, 0, 0);
}

// T1a: bijective chunked XCD swizzle + 8x8 supertile (needs gx%8==0, gy%8==0).
__device__ __forceinline__ void swz_tile(int& tileY, int& tileX) {
  const int gx = gridDim.x, gy = gridDim.y;
  const int L = blockIdx.y * gx + blockIdx.x;
  const int q = (gx * gy) >> 3;
  const int s = (L & 7) * q + (L >> 3);
  const int sid = s >> 6;
  const int t = s & 63;
  const int scols = gx >> 3;
  const int sy = sid / scols, sx = sid - sy * scols;
  tileY = sy * 8 + (t >> 3);
  tileX = sx * 8 + (t & 7);
}

// T1b: plain bijective chunked swizzle (needs nwg%8==0 only).
__device__ __forceinline__ void swz_lin(int& tileY, int& tileX) {
  const int gx = gridDim.x;
  const int nwg = gx * gridDim.y;
  const int L = blockIdx.y * gx + blockIdx.x;
  const int s = (L & 7) * (nwg >> 3) + (L >> 3);
  tileY = s / gx;
  tileX = s - tileY * gx;
}

// ---------------- pass 0 ----------------
__global__ void k_convert8(const float* __restrict__ in, unsigned char* __restrict__ out, long n8) {
  long i = (long)blockIdx.x * blockDim.x + threadIdx.x;
  long stride = (long)gridDim.x * blockDim.x;
  for (; i < n8; i += stride) {
    float4 a = reinterpret_cast<const float4*>(in)[i * 2];
    float4 b = reinterpret_cast<const float4*>(in)[i * 2 + 1];
    int w0 = __builtin_amdgcn_cvt_pk_fp8_f32(a.x, a.y, 0, false);
    w0 = __builtin_amdgcn_cvt_pk_fp8_f32(a.z, a.w, w0, true);
    int w1 = __builtin_amdgcn_cvt_pk_fp8_f32(b.x, b.y, 0, false);
    w1 = __builtin_amdgcn_cvt_pk_fp8_f32(b.z, b.w, w1, true);
    reinterpret_cast<int2*>(out)[i] = make_int2(w0, w1);
  }
}

__global__ void k_copy4(const float4* __restrict__ in, float4* __restrict__ out, long n4) {
  long i = (long)blockIdx.x * blockDim.x + threadIdx.x;
  long stride = (long)gridDim.x * blockDim.x;
  for (; i < n4; i += stride) out[i] = in[i];
}

// Mt8[n][k] = fp8(M[k][n])
__global__ void k_transpose_fp8(const float* __restrict__ M, unsigned char* __restrict__ Mt) {
  __shared__ float t[32][33];
  int bx = blockIdx.x * 32, by = blockIdx.y * 32;
  int tx = threadIdx.x, ty = threadIdx.y;
#pragma unroll
  for (int i = 0; i < 32; i += 8)
    t[ty + i][tx] = M[(size_t)(by + ty + i) * D_DIM + bx + tx];
  __syncthreads();
#pragma unroll
  for (int i = 0; i < 32; i += 8) {
    float v = t[tx][ty + i];
    int p = __builtin_amdgcn_cvt_pk_fp8_f32(v, v, 0, false);
    Mt[(size_t)(bx + ty + i) * D_DIM + by + tx] = (unsigned char)(p & 0xFF);
  }
}

// ======== shared 4-phase MX-fp8 mainloop: 256x256 tile, BK=128 ========
// 8 waves (2M x 4N), wave tile 128x64, acc[8][4]=128 regs. LDS 128 KiB dbuf.
// mfma_scale_f32_16x16x128_f8f6f4, unit scales (E8M0=127 -> x1.0): exact fp8
// math at 2x the non-scaled rate. Each 32B operand rep = two b128 at granules
// (lhi, lhi+4) [R19 fix: these reproduce R17's measured-0-conflict pattern;
// (2lhi,2lhi+1) collapsed to 4x 32B classes -> 4-way conflict], phys slot =
// g ^ (row&7). K-permutation shared by A and B -> GEMM sum exact.
__device__ __forceinline__ void mainloop4ph(const unsigned char* __restrict__ ga,
                                            const unsigned char* __restrict__ gb,
                                            unsigned char* As, unsigned char* Bs,
                                            int aRow0, int bRow0, int lhi, int tid,
                                            f32x4 acc[8][4]) {
  const int nt = D_DIM / 128;                    // 24
#pragma unroll
  for (int j = 0; j < 4; ++j) {
    gload16(ga + (size_t)j * 64 * D_DIM, As + j * 8192 + tid * 16);
    gload16(gb + (size_t)j * 64 * D_DIM, Bs + j * 8192 + tid * 16);
  }
  const int g0 = lhi, g1 = lhi ^ 4;              // R19: two 4-consecutive granule sets
  for (int t = 0; t < nt; ++t) {
    const int p = t & 1;
    const unsigned char* Ac = As + p * 32768;
    const unsigned char* Bc = Bs + p * 32768;
    unsigned char* An = As + (p ^ 1) * 32768;
    unsigned char* Bn = Bs + (p ^ 1) * 32768;
    const bool stage = (t + 1 < nt);
    const int k1 = (t + 1) * 128;
    asm volatile("s_waitcnt vmcnt(0)" ::: "memory");   // tile-t units landed
    __builtin_amdgcn_s_barrier();
    __builtin_amdgcn_sched_barrier(0);
    i32x8 b8[4];

#define XPH(q)                                                                      \
    {                                                                              \
      if ((q) == 0) {                                                              \
        _Pragma("unroll") for (int n = 0; n < 4; ++n) {                            \
          const int row = bRow0 + n * 16;                                          \
          const int f = row & 7;                                                   \
          i32x4 lo = *reinterpret_cast<const i32x4*>(&Bc[row * 128 + ((g0 ^ f) * 16)]); \
          i32x4 hi = *reinterpret_cast<const i32x4*>(&Bc[row * 128 + ((g1 ^ f) * 16)]); \
          b8[n] = cmb(lo, hi);                                                     \
        }                                                                          \
      }                                                                            \
      i32x8 a80, a81;                                                              \
      {                                                                            \
        const int r0 = aRow0 + (q) * 32;                                           \
        const int f0 = r0 & 7;                                                     \
        i32x4 lo = *reinterpret_cast<const i32x4*>(&Ac[r0 * 128 + ((g0 ^ f0) * 16)]); \
        i32x4 hi = *reinterpret_cast<const i32x4*>(&Ac[r0 * 128 + ((g1 ^ f0) * 16)]); \
        a80 = cmb(lo, hi);                                                         \
        const int r1 = r0 + 16;                                                    \
        const int f1 = r1 & 7;                                                     \
        lo = *reinterpret_cast<const i32x4*>(&Ac[r1 * 128 + ((g0 ^ f1) * 16)]);    \
        hi = *reinterpret_cast<const i32x4*>(&Ac[r1 * 128 + ((g1 ^ f1) * 16)]);    \
        a81 = cmb(lo, hi);                                                         \
      }                                                                            \
      if (stage) {                                                                 \
        gload16(ga + (size_t)(q) * 64 * D_DIM + k1, An + (q) * 8192 + tid * 16);   \
        gload16(gb + (size_t)(q) * 64 * D_DIM + k1, Bn + (q) * 8192 + tid * 16);   \
      }                                                                            \
      __builtin_amdgcn_s_barrier();                                                \
      __builtin_amdgcn_sched_barrier(0);                                           \
      __builtin_amdgcn_s_setprio(1);                                               \
      _Pragma("unroll") for (int n = 0; n < 4; ++n) {                              \
        acc[(q) * 2][n] = __builtin_amdgcn_mfma_scale_f32_16x16x128_f8f6f4(        \
            a80, b8[n], acc[(q) * 2][n], 0, 0, 0, 127, 0, 127);                    \
        acc[(q) * 2 + 1][n] = __builtin_amdgcn_mfma_scale_f32_16x16x128_f8f6f4(    \
            a81, b8[n], acc[(q) * 2 + 1][n], 0, 0, 0, 127, 0, 127);                \
      }                                                                            \
      __builtin_amdgcn_s_setprio(0);                                               \
      __builtin_amdgcn_s_barrier();                                                \
      __builtin_amdgcn_sched_barrier(0);                                           \
    }

    XPH(0) XPH(1) XPH(2) XPH(3)
#undef XPH
  }
}

// ---- GEMM1: X @ M, MX-fp8. Epilogue: norm2 dot vs f32 X (+ optional sM8) ----
template <bool WRITE_SM>
__global__ __launch_bounds__(512, 2) void k_gemm_xm8(const unsigned char* __restrict__ X8,
                                                     const unsigned char* __restrict__ Mt8,
                                                     const float* __restrict__ Xf,
                                                     unsigned char* __restrict__ smOut,
                                                     float* __restrict__ norm) {
  __shared__ unsigned char As[2 * 256 * 128], Bs[2 * 256 * 128];
  const int tid = threadIdx.x, lane = tid & 63, wave = tid >> 6;
  const int wm = wave >> 2, wn = wave & 3;       // 2M x 4N
  const int l15 = lane & 15, lhi = lane >> 4;
  int tileY, tileX;
  swz_lin(tileY, tileX);
  const int rowBase = tileY * 256, colBase = tileX * 256;
  const int srow = tid >> 3, ssl = tid & 7;
  const unsigned char* ga = X8 + (size_t)(rowBase + srow) * D_DIM + ((ssl ^ (srow & 7)) * 16);
  const unsigned char* gb = Mt8 + (size_t)(colBase + srow) * D_DIM + ((ssl ^ (srow & 7)) * 16);
  f32x4 acc[8][4] = {};
  mainloop4ph(ga, gb, As, Bs, wm * 128 + l15, wn * 64 + l15, lhi, tid, acc);
  __syncthreads();

  const int c0 = colBase + wn * 64 + l15;
#pragma unroll
  for (int m = 0; m < 8; ++m) {
#pragma unroll
    for (int r = 0; r < 4; ++r) {
      const size_t grow = rowBase + wm * 128 + m * 16 + lhi * 4 + r;
      float v = 0.f;
#pragma unroll
      for (int n = 0; n < 4; ++n) {
        float a = acc[m][n][r];
        const int gcol = c0 + n * 16;
        v += a * Xf[grow * D_DIM + gcol];
        if (WRITE_SM) {
          int pk = __builtin_amdgcn_cvt_pk_fp8_f32(a, a, 0, false);
          smOut[grow * D_DIM + gcol] = (unsigned char)(pk & 0xFF);
        }
      }
      v += __shfl_xor(v, 1); v += __shfl_xor(v, 2);
      v += __shfl_xor(v, 4); v += __shfl_xor(v, 8);
      if ((lane & 15) == 0) atomicAdd(&norm[grow], v);
    }
  }
}

// ---- GEMM2: MX-fp8 4-phase, STORE-ONLY epilogue -> bf16 S half ----
__global__ __launch_bounds__(512, 2) void k_gemm_cross(const unsigned char* __restrict__ sM8,
                                                       const unsigned char* __restrict__ xte8h,
                                                       const float* __restrict__ sn2,
                                                       const float* __restrict__ cn2h,
                                                       unsigned short* __restrict__ S) {
  __shared__ unsigned char As[2 * 256 * 128], Bs[2 * 256 * 128];
  const int tid = threadIdx.x, lane = tid & 63, wave = tid >> 6;
  const int wm = wave >> 2, wn = wave & 3;
  const int l15 = lane & 15, lhi = lane >> 4;
  int tileY, tileX;
  swz_tile(tileY, tileX);
  const int rowBase = tileY * 256, colBase = tileX * 256;
  const int srow = tid >> 3, ssl = tid & 7;
  const unsigned char* ga = sM8 + (size_t)(rowBase + srow) * D_DIM + ((ssl ^ (srow & 7)) * 16);
  const unsigned char* gb = xte8h + (size_t)(colBase + srow) * D_DIM + ((ssl ^ (srow & 7)) * 16);
  const int bRow0 = wn * 64 + l15;
  f32x4 acc[8][4] = {};
  mainloop4ph(ga, gb, As, Bs, wm * 128 + l15, bRow0, lhi, tid, acc);
  __syncthreads();

  float* snlds = reinterpret_cast<float*>(As);     // [256]
  if (tid < 256) snlds[tid] = sn2[rowBase + tid];
  __syncthreads();
  float cn[4];
#pragma unroll
  for (int n = 0; n < 4; ++n) cn[n] = cn2h[colBase + bRow0 + n * 16];
#pragma unroll
  for (int m = 0; m < 8; ++m) {
#pragma unroll
    for (int r = 0; r < 4; ++r) {
      const int lrow = wm * 128 + m * 16 + lhi * 4 + r;
      const float sn = snlds[lrow];
      const size_t grow = rowBase + lrow;
#pragma unroll
      for (int n = 0; n < 4; ++n) {
        float d2 = sn + cn[n] - 2.f * acc[m][n][r];
        float kv = exp2f(-0.14426950408889634f * sqrtf(fmaxf(d2, 0.f)));
        S[grow * 4096 + colBase + bRow0 + n * 16] = f2bf(kv);
      }
    }
  }
}

// ---- k_out: column-wise weighted reduction of one half of S -> part ----
__global__ __launch_bounds__(256) void k_out(const unsigned short* __restrict__ S,
                                             const float* __restrict__ Y,
                                             float* __restrict__ part, int halfBase) {
  __shared__ float ylds[256 * 10];
  const int tid = threadIdx.x;
  const int sBase = blockIdx.y * 256;
  const int tloc = blockIdx.x * 256 + tid;       // 0..4095
  const int tglob = halfBase + tloc;
  for (int i = tid; i < 2560; i += 256) ylds[i] = Y[(size_t)sBase * 10 + i];
  __syncthreads();
  float num[10] = {0, 0, 0, 0, 0, 0, 0, 0, 0, 0};
  float den = 0.f;
  for (int s = 0; s < 256; ++s) {
    float kv = bf2f(S[(size_t)(sBase + s) * 4096 + tloc]);
    const float* yr = &ylds[s * 10];
#pragma unroll
    for (int c = 0; c < 10; ++c) num[c] += kv * yr[c];
    den += kv;
  }
#pragma unroll
  for (int c = 0; c < 10; ++c)
    part[((size_t)blockIdx.y * 11 + c) * NTEST + tglob] = num[c];
  part[((size_t)blockIdx.y * 11 + 10) * NTEST + tglob] = den;
}

// ---------------- final reduce ----------------
__global__ void k_reduce(const float* __restrict__ part, float* __restrict__ out) {
  int t = blockIdx.x * blockDim.x + threadIdx.x;
  float num[10] = {0, 0, 0, 0, 0, 0, 0, 0, 0, 0};
  float den = 0.f;
  for (int it = 0; it < NTRAIN / 256; ++it) {
    const float* p = part + (size_t)it * 11 * NTEST + t;
#pragma unroll
    for (int c = 0; c < 10; ++c) num[c] += p[(size_t)c * NTEST];
    den += p[(size_t)10 * NTEST];
  }
  float inv = 1.f / den;
#pragma unroll
  for (int c = 0; c < 10; ++c) out[(size_t)t * 10 + c] = num[c] * inv;
}

extern "C" void kernel_launch(void* const* d_in, const int* in_sizes, int n_in,
                              void* d_out, int out_size, void* d_ws, size_t ws_size,
                              hipStream_t stream) {
  const float* x_train = (const float*)d_in[0];
  const float* y_train = (const float*)d_in[1];
  const float* x_test  = (const float*)d_in[2];
  const float* M       = (const float*)d_in[3];
  float* out = (float*)d_out;

  char* ws = (char*)d_ws;
  unsigned char*  xtr8 = (unsigned char*)(ws + 0);            // 50331648
  unsigned char*  xte8 = (unsigned char*)(ws + 50331648);     // 25165824
  unsigned char*  Mt8  = (unsigned char*)(ws + 75497472);     // 9437184
  unsigned char*  sM8  = (unsigned char*)(ws + 84934656);     // 50331648
  float* s_n2 = (float*)(ws + 135266304);                     // 65536
  float* c_n2 = (float*)(ws + 135331840);                     // 32768
  float* part = (float*)(ws + 135364608);                     // 23068672
  unsigned short* S = (unsigned short*)(ws + 158433280);      // 134217728

  hipMemsetAsync(ws + 135266304, 0, 98304, stream);  // s_n2 + c_n2

  k_convert8<<<1024, 256, 0, stream>>>(x_train, xtr8, (long)NTRAIN * D_DIM / 8);
  k_convert8<<<1024, 256, 0, stream>>>(x_test, xte8, (long)NTEST * D_DIM / 8);
  k_transpose_fp8<<<dim3(96, 96), dim3(32, 8), 0, stream>>>(M, Mt8);
  k_copy4<<<2048, 256, 0, stream>>>((const float4*)M, (float4*)(out + 81920),
                                    (long)D_DIM * D_DIM / 4);

  k_gemm_xm8<true><<<dim3(12, 64), 512, 0, stream>>>(xtr8, Mt8, x_train, sM8, s_n2);
  k_gemm_xm8<false><<<dim3(12, 32), 512, 0, stream>>>(xte8, Mt8, x_test, nullptr, c_n2);

  for (int h = 0; h < 2; ++h) {
    k_gemm_cross<<<dim3(16, 64), 512, 0, stream>>>(
        sM8, xte8 + (size_t)h * 4096 * D_DIM, s_n2, c_n2 + h * 4096, S);
    k_out<<<dim3(16, 64), 256, 0, stream>>>(S, y_train, part, h * 4096);
  }
  k_reduce<<<32, 256, 0, stream>>>(part, out);
}